// Round 2
// baseline (2945.772 us; speedup 1.0000x reference)
//
#include <hip/hip_runtime.h>

#define SKIPF 0.70710678118654752440f

typedef unsigned short u16;
typedef unsigned int u32;
typedef __attribute__((ext_vector_type(4))) short bf16x4;
typedef __attribute__((ext_vector_type(8))) short bf16x8;
typedef __attribute__((ext_vector_type(4))) float f32x4;

#define MFMA32(A, B, C) __builtin_amdgcn_mfma_f32_16x16x32_bf16(A, B, C, 0, 0, 0)
#define MFMA16(A, B, C) __builtin_amdgcn_mfma_f32_16x16x16bf16_1k(A, B, C, 0, 0, 0)

__device__ __forceinline__ float bf2f(u16 v) {
  u32 u = ((u32)v) << 16; float f; __builtin_memcpy(&f, &u, 4); return f;
}
__device__ __forceinline__ u16 f2bf(float f) {
  u32 u; __builtin_memcpy(&u, &f, 4);
  u = (u + 0x7fffu + ((u >> 16) & 1u)) >> 16;
  return (u16)u;
}
__device__ __forceinline__ void gload16(const void* g, void* s) {
  __builtin_amdgcn_global_load_lds((const __attribute__((address_space(1))) void*)g,
                                   (__attribute__((address_space(3))) void*)s, 16, 0, 0);
}

// ---------------- small prep kernels ----------------

__global__ void copy_f32_kernel(const float4* __restrict__ src, float4* __restrict__ dst, int n) {
  int i = blockIdx.x * blockDim.x + threadIdx.x;
  if (i < n) dst[i] = src[i];
}

__global__ void silu_prep_kernel(const float* __restrict__ c, const float* __restrict__ t,
                                 float* __restrict__ silu_c) {
  int i = blockIdx.x * 256 + threadIdx.x;  // 4096 = B*DIM
  float x = (c[i] + t[i]) * SKIPF;
  silu_c[i] = x / (1.f + __expf(-x));
}

// mod partials: grid (24, 16); block 256. n = bx*256+tid; k-chunk 64 per by.
__global__ void adaln_part_kernel(const float* __restrict__ silu_c, const float* __restrict__ aw,
                                  float* __restrict__ part) {
  __shared__ float sc[4][64];
  int n = blockIdx.x * 256 + threadIdx.x;
  int ks = blockIdx.y;
  int k0 = ks * 64;
  int b = threadIdx.x >> 6, kk = threadIdx.x & 63;
  sc[b][kk] = silu_c[b * 1024 + k0 + kk];
  __syncthreads();
  float a0 = 0.f, a1 = 0.f, a2 = 0.f, a3 = 0.f;
  for (int k = 0; k < 64; ++k) {
    float w = aw[(size_t)(k0 + k) * 6144 + n];
    a0 += sc[0][k] * w; a1 += sc[1][k] * w; a2 += sc[2][k] * w; a3 += sc[3][k] * w;
  }
  part[(size_t)(ks * 4 + 0) * 6144 + n] = a0;
  part[(size_t)(ks * 4 + 1) * 6144 + n] = a1;
  part[(size_t)(ks * 4 + 2) * 6144 + n] = a2;
  part[(size_t)(ks * 4 + 3) * 6144 + n] = a3;
}

__global__ void adaln_reduce_kernel(const float* __restrict__ part, const float* __restrict__ ab,
                                    float* __restrict__ mod) {
  int i = blockIdx.x * 256 + threadIdx.x;  // 24576 = 4*6144
  int b = i / 6144, n = i - b * 6144;
  float a = ab[n];
  for (int ks = 0; ks < 16; ++ks) a += part[(size_t)(ks * 4 + b) * 6144 + n];
  mod[(size_t)b * 6144 + n] = a;
}

// W (K x N) f32 -> WT (N x K) bf16. block (32,8), grid (N/32, K/32)
__global__ void wtrans_kernel(const float* __restrict__ W, u16* __restrict__ WT, int K, int N) {
  __shared__ float tile[32][33];
  int n0 = blockIdx.x * 32, k0 = blockIdx.y * 32;
  int tx = threadIdx.x, ty = threadIdx.y;
#pragma unroll
  for (int i = 0; i < 4; ++i)
    tile[ty * 4 + i][tx] = W[(size_t)(k0 + ty * 4 + i) * N + n0 + tx];
  __syncthreads();
#pragma unroll
  for (int i = 0; i < 4; ++i)
    WT[(size_t)(n0 + ty * 4 + i) * K + k0 + tx] = f2bf(tile[tx][ty * 4 + i]);
}

// LN + adaLN modulate: h = (ln(x)*(1+sc) + sh) * SKIP -> bf16. one block per row.
__global__ __launch_bounds__(256) void ln_mod_kernel(const float* __restrict__ x,
                                                     const float* __restrict__ mod,
                                                     u16* __restrict__ h, int sh_off, int sc_off) {
  int row = blockIdx.x;
  int b = row >> 10;
  const float4* xr = (const float4*)(x + (size_t)row * 1024);
  float4 v = xr[threadIdx.x];
  float s = v.x + v.y + v.z + v.w;
  float ss = v.x * v.x + v.y * v.y + v.z * v.z + v.w * v.w;
#pragma unroll
  for (int o = 32; o; o >>= 1) { s += __shfl_xor(s, o); ss += __shfl_xor(ss, o); }
  __shared__ float red[8];
  int wave = threadIdx.x >> 6;
  if ((threadIdx.x & 63) == 0) { red[wave * 2] = s; red[wave * 2 + 1] = ss; }
  __syncthreads();
  s = red[0] + red[2] + red[4] + red[6];
  ss = red[1] + red[3] + red[5] + red[7];
  float mu = s * (1.f / 1024.f);
  float var = ss * (1.f / 1024.f) - mu * mu;
  float rs = rsqrtf(var + 1e-6f);
  int n = threadIdx.x * 4;
  const float* mb = mod + (size_t)b * 6144;
  float4 sc = *(const float4*)(mb + sc_off + n);
  float4 sh = *(const float4*)(mb + sh_off + n);
  ushort4 o4;
  o4.x = f2bf(((v.x - mu) * rs * (1.f + sc.x) + sh.x) * SKIPF);
  o4.y = f2bf(((v.y - mu) * rs * (1.f + sc.y) + sh.y) * SKIPF);
  o4.z = f2bf(((v.z - mu) * rs * (1.f + sc.z) + sh.z) * SKIPF);
  o4.w = f2bf(((v.w - mu) * rs * (1.f + sc.w) + sh.w) * SKIPF);
  *(ushort4*)(h + (size_t)row * 1024 + n) = o4;
}

// ---------------- GEMM: C(MxN) = A(MxK,bf16) @ BT(NxK,bf16)^T + bias ----------------
// EPI 0: -> bf16 Cb.  EPI 1: gelu -> bf16 Cb.  EPI 2: x = (x + g*val)*SKIP (f32, N==1024)
template <int EPI>
__global__ __launch_bounds__(256) void gemm_kernel(
    const u16* __restrict__ A, const u16* __restrict__ BT, const float* __restrict__ bias,
    u16* __restrict__ Cb, float* __restrict__ xio, const float* __restrict__ mod, int g_off,
    int M, int N, int K) {
  __shared__ u16 As[128 * 32];
  __shared__ u16 Bs[128 * 32];
  const int tid = threadIdx.x;
  const int lane = tid & 63, wave = tid >> 6;
  const int lq = lane & 15, lk = lane >> 4;
  const int wr = wave >> 1, wc = wave & 1;
  const int m0 = blockIdx.y * 128, n0 = blockIdx.x * 128;

  const int srow = tid >> 2;
  const int skc = (tid & 3) * 8;
  const u16* Ag0 = A + (size_t)(m0 + srow) * K + skc;
  const u16* Ag1 = A + (size_t)(m0 + 64 + srow) * K + skc;
  const u16* Bg0 = BT + (size_t)(n0 + srow) * K + skc;
  const u16* Bg1 = BT + (size_t)(n0 + 64 + srow) * K + skc;
  char* AsB = (char*)As;
  char* BsB = (char*)Bs;

  f32x4 acc[4][4];
#pragma unroll
  for (int i = 0; i < 4; ++i)
#pragma unroll
    for (int j = 0; j < 4; ++j) acc[i][j] = (f32x4){0.f, 0.f, 0.f, 0.f};

  const bf16x8* Av = (const bf16x8*)As;
  const bf16x8* Bv = (const bf16x8*)Bs;

  for (int kt = 0; kt < K; kt += 32) {
    gload16(Ag0 + kt, AsB + tid * 16);
    gload16(Ag1 + kt, AsB + 4096 + tid * 16);
    gload16(Bg0 + kt, BsB + tid * 16);
    gload16(Bg1 + kt, BsB + 4096 + tid * 16);
    __syncthreads();
    bf16x8 af[4], bfr[4];
#pragma unroll
    for (int i = 0; i < 4; ++i) {
      af[i] = Av[((wr * 64 + i * 16 + lq) * 32 + lk * 8) >> 3];
      bfr[i] = Bv[((wc * 64 + i * 16 + lq) * 32 + lk * 8) >> 3];
    }
#pragma unroll
    for (int i = 0; i < 4; ++i)
#pragma unroll
      for (int j = 0; j < 4; ++j) acc[i][j] = MFMA32(af[i], bfr[j], acc[i][j]);
    __syncthreads();
  }

#pragma unroll
  for (int i = 0; i < 4; ++i) {
    int rbase = m0 + wr * 64 + i * 16 + lk * 4;
#pragma unroll
    for (int j = 0; j < 4; ++j) {
      int cg = n0 + wc * 64 + j * 16 + lq;
      float bv = bias[cg];
#pragma unroll
      for (int r = 0; r < 4; ++r) {
        int row = rbase + r;
        float val = acc[i][j][r] + bv;
        if (EPI == 0) {
          Cb[(size_t)row * N + cg] = f2bf(val);
        } else if (EPI == 1) {
          float tt = 0.7978845608028654f * (val + 0.044715f * val * val * val);
          float e = __expf(2.f * tt);
          float th = 1.f - 2.f / (e + 1.f);
          Cb[(size_t)row * N + cg] = f2bf(0.5f * val * (1.f + th));
        } else {
          int b = row >> 10;
          float g = mod[(size_t)b * 6144 + g_off + cg];
          float xv = xio[(size_t)row * 1024 + cg];
          xio[(size_t)row * 1024 + cg] = (xv + g * val) * SKIPF;
        }
      }
    }
  }
}

// ---------------- RoPE + scatter qkv -> q,k,v [b][h][l][d] ----------------
__global__ __launch_bounds__(256) void rope_scatter_kernel(
    const u16* __restrict__ qkv, const float* __restrict__ cosb, const float* __restrict__ sinb,
    u16* __restrict__ qo, u16* __restrict__ ko, u16* __restrict__ vo) {
  int m = blockIdx.x;
  int b = m >> 10, l = m & 1023;
  size_t base = (size_t)m * 3072;
  int t = threadIdx.x;
#pragma unroll
  for (int it = 0; it < 2; ++it) {
    int pi = t + it * 256;  // 0..511 pair slots
    int hh = pi >> 5, pr = pi & 31;
    int d0 = pr * 2;
    float cc = cosb[l * 64 + d0], sn = sinb[l * 64 + d0];
    size_t dst = ((size_t)(b * 16 + hh) * 1024 + l) * 64 + d0;
    u32 qp = *(const u32*)(qkv + base + hh * 64 + d0);
    float q0 = bf2f((u16)(qp & 0xffff)), q1 = bf2f((u16)(qp >> 16));
    u32 rq = (u32)f2bf(q0 * cc - q1 * sn) | ((u32)f2bf(q1 * cc + q0 * sn) << 16);
    *(u32*)(qo + dst) = rq;
    u32 kp = *(const u32*)(qkv + base + 1024 + hh * 64 + d0);
    float k0 = bf2f((u16)(kp & 0xffff)), k1 = bf2f((u16)(kp >> 16));
    u32 rk = (u32)f2bf(k0 * cc - k1 * sn) | ((u32)f2bf(k1 * cc + k0 * sn) << 16);
    *(u32*)(ko + dst) = rk;
  }
#pragma unroll
  for (int it = 0; it < 2; ++it) {
    int pi = t + it * 256;
    int hh = pi >> 5, pr = pi & 31;
    int d0 = pr * 2;
    u32 vp = *(const u32*)(qkv + base + 2048 + hh * 64 + d0);
    *(u32*)(vo + ((size_t)(b * 16 + hh) * 1024 + l) * 64 + d0) = vp;
  }
}

// ---------------- flash attention, 16 q-rows per wave, swapped QK^T ----------------
__global__ __launch_bounds__(256) void attn_kernel(const u16* __restrict__ qb,
                                                   const u16* __restrict__ kb,
                                                   const u16* __restrict__ vb,
                                                   u16* __restrict__ ob) {
  int bh = blockIdx.y;
  int qt = blockIdx.x;
  int lane = threadIdx.x & 63, wave = threadIdx.x >> 6;
  int lq = lane & 15, lk = lane >> 4;
  const u16* Q = qb + (size_t)bh * 65536;
  const u16* Kp = kb + (size_t)bh * 65536;
  const u16* V = vb + (size_t)bh * 65536;
  int qbase = qt * 64 + wave * 16;
  bf16x8 qf0 = *(const bf16x8*)(Q + (size_t)(qbase + lq) * 64 + lk * 8);
  bf16x8 qf1 = *(const bf16x8*)(Q + (size_t)(qbase + lq) * 64 + 32 + lk * 8);
  float mrun = -1e30f, lsum = 0.f;
  f32x4 oacc[4];
#pragma unroll
  for (int f = 0; f < 4; ++f) oacc[f] = (f32x4){0.f, 0.f, 0.f, 0.f};
  const f32x4 z4 = (f32x4){0.f, 0.f, 0.f, 0.f};
  for (int kvb = 0; kvb < 1024; kvb += 16) {
    bf16x8 kf0 = *(const bf16x8*)(Kp + (size_t)(kvb + lq) * 64 + lk * 8);
    bf16x8 kf1 = *(const bf16x8*)(Kp + (size_t)(kvb + lq) * 64 + 32 + lk * 8);
    f32x4 st = MFMA32(kf0, qf0, z4);
    st = MFMA32(kf1, qf1, st);
    float s0 = st[0] * 0.125f, s1 = st[1] * 0.125f, s2 = st[2] * 0.125f, s3 = st[3] * 0.125f;
    float pm = fmaxf(fmaxf(s0, s1), fmaxf(s2, s3));
    pm = fmaxf(pm, __shfl_xor(pm, 16));
    pm = fmaxf(pm, __shfl_xor(pm, 32));
    float mnew = fmaxf(mrun, pm);
    float corr = __expf(mrun - mnew);
    mrun = mnew;
    float p0 = __expf(s0 - mnew), p1 = __expf(s1 - mnew);
    float p2 = __expf(s2 - mnew), p3 = __expf(s3 - mnew);
    float ps = p0 + p1 + p2 + p3;
    ps += __shfl_xor(ps, 16);
    ps += __shfl_xor(ps, 32);
    lsum = lsum * corr + ps;
    bf16x4 pf;
    pf[0] = (short)f2bf(p0); pf[1] = (short)f2bf(p1);
    pf[2] = (short)f2bf(p2); pf[3] = (short)f2bf(p3);
    float c0 = __shfl(corr, lk * 4 + 0), c1 = __shfl(corr, lk * 4 + 1);
    float c2 = __shfl(corr, lk * 4 + 2), c3 = __shfl(corr, lk * 4 + 3);
#pragma unroll
    for (int f = 0; f < 4; ++f) {
      oacc[f][0] *= c0; oacc[f][1] *= c1; oacc[f][2] *= c2; oacc[f][3] *= c3;
    }
#pragma unroll
    for (int f = 0; f < 4; ++f) {
      bf16x4 vf;
#pragma unroll
      for (int i = 0; i < 4; ++i)
        vf[i] = (short)V[(size_t)(kvb + lk * 4 + i) * 64 + lq + f * 16];
      oacc[f] = MFMA16(pf, vf, oacc[f]);
    }
  }
  float inv = 1.f / lsum;
  float i0 = __shfl(inv, lk * 4 + 0), i1 = __shfl(inv, lk * 4 + 1);
  float i2 = __shfl(inv, lk * 4 + 2), i3 = __shfl(inv, lk * 4 + 3);
  int b = bh >> 4, hh = bh & 15;
#pragma unroll
  for (int f = 0; f < 4; ++f) {
#pragma unroll
    for (int j = 0; j < 4; ++j) {
      int qrow = qbase + lk * 4 + j;
      float sc = (j == 0) ? i0 : (j == 1) ? i1 : (j == 2) ? i2 : i3;
      ob[((size_t)(b * 1024 + qrow)) * 1024 + hh * 64 + lq + f * 16] = f2bf(oacc[f][j] * sc);
    }
  }
}

// ---------------- launch ----------------

extern "C" void kernel_launch(void* const* d_in, const int* in_sizes, int n_in,
                              void* d_out, int out_size, void* d_ws, size_t ws_size,
                              hipStream_t stream) {
  const float* x = (const float*)d_in[0];
  const float* c = (const float*)d_in[1];
  const float* t = (const float*)d_in[2];
  const float* cosb = (const float*)d_in[4];
  const float* sinb = (const float*)d_in[5];
  const float* qkv_w = (const float*)d_in[6];
  const float* qkv_b = (const float*)d_in[7];
  const float* proj_w = (const float*)d_in[8];
  const float* proj_b = (const float*)d_in[9];
  const float* w1 = (const float*)d_in[10];
  const float* b1 = (const float*)d_in[11];
  const float* w2 = (const float*)d_in[12];
  const float* b2 = (const float*)d_in[13];
  const float* aw = (const float*)d_in[14];
  const float* ab = (const float*)d_in[15];

  constexpr size_t OFF_X = 0;                          // 16 MB f32 residual
  constexpr size_t OFF_H = OFF_X + 16777216;           // 8 MB bf16 h
  constexpr size_t OFF_BIG = OFF_H + 8388608;          // 32 MB bf16 qkv / m1
  constexpr size_t OFF_Q = OFF_BIG + 33554432;         // 8 MB
  constexpr size_t OFF_K = OFF_Q + 8388608;
  constexpr size_t OFF_V = OFF_K + 8388608;
  constexpr size_t OFF_AO = OFF_V + 8388608;
  constexpr size_t OFF_WQ = OFF_AO + 8388608;          // 6 MB bf16 qkv_w^T
  constexpr size_t OFF_WP = OFF_WQ + 6291456;          // 2 MB
  constexpr size_t OFF_W1 = OFF_WP + 2097152;          // 8 MB
  constexpr size_t OFF_W2 = OFF_W1 + 8388608;          // 8 MB
  constexpr size_t OFF_SC = OFF_W2 + 8388608;          // silu_c 16 KB
  constexpr size_t OFF_MOD = OFF_SC + 16384;           // mod 96 KB
  constexpr size_t OFF_PART = OFF_MOD + 98304;         // partials 1.5 MB

  char* ws = (char*)d_ws;
  float* x_cur = (float*)(ws + OFF_X);
  u16* h = (u16*)(ws + OFF_H);
  u16* big = (u16*)(ws + OFF_BIG);
  u16* qv = (u16*)(ws + OFF_Q);
  u16* kv = (u16*)(ws + OFF_K);
  u16* vv = (u16*)(ws + OFF_V);
  u16* ao = (u16*)(ws + OFF_AO);
  u16* wTq = (u16*)(ws + OFF_WQ);
  u16* wTp = (u16*)(ws + OFF_WP);
  u16* wT1 = (u16*)(ws + OFF_W1);
  u16* wT2 = (u16*)(ws + OFF_W2);
  float* silu_c = (float*)(ws + OFF_SC);
  float* mod = (float*)(ws + OFF_MOD);
  float* part = (float*)(ws + OFF_PART);

  copy_f32_kernel<<<4096, 256, 0, stream>>>((const float4*)x, (float4*)x_cur, 1048576);
  silu_prep_kernel<<<16, 256, 0, stream>>>(c, t, silu_c);

  for (int L = 0; L < 8; ++L) {
    const float* awL = aw + (size_t)L * 1024 * 6144;
    const float* abL = ab + (size_t)L * 6144;
    const float* qwL = qkv_w + (size_t)L * 1024 * 3072;
    const float* qbL = qkv_b + (size_t)L * 3072;
    const float* pwL = proj_w + (size_t)L * 1024 * 1024;
    const float* pbL = proj_b + (size_t)L * 1024;
    const float* w1L = w1 + (size_t)L * 1024 * 4096;
    const float* b1L = b1 + (size_t)L * 4096;
    const float* w2L = w2 + (size_t)L * 4096 * 1024;
    const float* b2L = b2 + (size_t)L * 1024;

    adaln_part_kernel<<<dim3(24, 16), 256, 0, stream>>>(silu_c, awL, part);
    adaln_reduce_kernel<<<96, 256, 0, stream>>>(part, abL, mod);

    wtrans_kernel<<<dim3(96, 32), dim3(32, 8), 0, stream>>>(qwL, wTq, 1024, 3072);
    wtrans_kernel<<<dim3(32, 32), dim3(32, 8), 0, stream>>>(pwL, wTp, 1024, 1024);
    wtrans_kernel<<<dim3(128, 32), dim3(32, 8), 0, stream>>>(w1L, wT1, 1024, 4096);
    wtrans_kernel<<<dim3(32, 128), dim3(32, 8), 0, stream>>>(w2L, wT2, 4096, 1024);

    ln_mod_kernel<<<4096, 256, 0, stream>>>(x_cur, mod, h, 0, 1024);
    gemm_kernel<0><<<dim3(24, 32), 256, 0, stream>>>(h, wTq, qbL, big, nullptr, nullptr, 0,
                                                     4096, 3072, 1024);
    rope_scatter_kernel<<<4096, 256, 0, stream>>>(big, cosb, sinb, qv, kv, vv);
    attn_kernel<<<dim3(16, 64), 256, 0, stream>>>(qv, kv, vv, ao);
    gemm_kernel<2><<<dim3(8, 32), 256, 0, stream>>>(ao, wTp, pbL, nullptr, x_cur, mod, 2048,
                                                    4096, 1024, 1024);
    ln_mod_kernel<<<4096, 256, 0, stream>>>(x_cur, mod, h, 3072, 4096);
    gemm_kernel<1><<<dim3(32, 32), 256, 0, stream>>>(h, wT1, b1L, big, nullptr, nullptr, 0,
                                                     4096, 4096, 1024);
    gemm_kernel<2><<<dim3(8, 32), 256, 0, stream>>>(big, wT2, b2L, nullptr, x_cur, mod, 5120,
                                                    4096, 1024, 4096);
  }

  copy_f32_kernel<<<4096, 256, 0, stream>>>((const float4*)x_cur, (float4*)d_out, 1048576);
}